// Round 1
// baseline (38.336 us; speedup 1.0000x reference)
//
#include <hip/hip_runtime.h>
#include <math.h>

#define NCLS 19
#define ACTC 18      // classes 1..18 contribute
#define BINS 51
#define NPIX 4096
#define NFEAT 256
#define TWO_PI_F 6.2831853071795864769f

// ws layout: float partial[ACTC*NFEAT]; int ncls[NCLS]
__global__ __launch_bounds__(256)
void hist_main(const float* __restrict__ x, const int* __restrict__ lab,
               float* __restrict__ partial, int* __restrict__ ncls) {
    const int f   = blockIdx.x;          // feature
    const int c   = blockIdx.y + 1;      // class 1..18
    const int tid = threadIdx.x;
    const int lane = tid & 63;
    const int wave = tid >> 6;

    __shared__ float xs[NPIX];
    __shared__ int   s_n;
    __shared__ float s_red[8];
    __shared__ float s_acc[4 * 64];

    if (tid == 0) s_n = 0;
    __syncthreads();

    // gather this class's pixel values for feature f into LDS
    const float* xrow = x + (size_t)f * NPIX;
    for (int p = tid; p < NPIX; p += 256) {
        if (lab[p] == c) {
            int slot = atomicAdd(&s_n, 1);
            xs[slot] = xrow[p];
        }
    }
    __syncthreads();
    const int n = s_n;
    if (f == 0 && tid == 0) ncls[c] = n;   // written every launch
    if (n == 0) {
        if (tid == 0) partial[blockIdx.y * NFEAT + f] = 0.0f;
        return;
    }

    // ---- stats: miu, var ----
    float s1 = 0.f, s2 = 0.f;
    for (int i = tid; i < n; i += 256) { float v = xs[i]; s1 += v; s2 += v * v; }
    for (int off = 32; off; off >>= 1) {
        s1 += __shfl_down(s1, off, 64);
        s2 += __shfl_down(s2, off, 64);
    }
    if (lane == 0) { s_red[wave] = s1; s_red[4 + wave] = s2; }
    __syncthreads();
    const float sum1 = s_red[0] + s_red[1] + s_red[2] + s_red[3];
    const float sum2 = s_red[4] + s_red[5] + s_red[6] + s_red[7];
    const float fn   = (float)n;
    const float miu  = sum1 / fn;
    const float m2   = sum2 / fn;
    const float var  = fmaxf(m2 - miu * miu, 1e-12f);
    const float var_s = var * 0.04f;     // var / 25

    // ---- KDE: lane <-> bin, waves split pixels ----
    const float binv = -5.0f + 0.2f * (float)lane;
    const float coef = -0.5f / var_s;
    float acc = 0.f;
    for (int i = wave; i < n; i += 4) {
        float d = binv - xs[i];          // LDS broadcast read
        acc += __expf(coef * d * d);
    }
    if (lane >= BINS) acc = 0.f;
    s_acc[wave * 64 + lane] = acc;
    __syncthreads();

    if (wave == 0) {
        float kde = s_acc[lane] + s_acc[64 + lane] + s_acc[128 + lane] + s_acc[192 + lane];
        float dt  = binv - miu;
        float tg  = __expf((-0.5f / var) * dt * dt);
        if (lane >= BINS) { kde = 0.f; tg = 0.f; }

        const float inv_s_vs = rsqrtf(TWO_PI_F * var_s);
        const float inv_s_v  = rsqrtf(TWO_PI_F * var);
        float sv = kde * inv_s_vs;
        float tt = tg  * inv_s_v;

        float ssum = sv, tsum = tt;
        for (int off = 32; off; off >>= 1) {
            ssum += __shfl_xor(ssum, off, 64);
            tsum += __shfl_xor(tsum, off, 64);
        }
        float hist  = sv / fmaxf(ssum, 1e-12f);
        float tnorm = tt / tsum;
        float diff  = hist - tnorm;
        float ad    = fabsf(diff);
        float sl1   = (ad < 1.0f) ? 0.5f * diff * diff : (ad - 0.5f);
        if (lane >= BINS) sl1 = 0.f;
        for (int off = 32; off; off >>= 1) sl1 += __shfl_xor(sl1, off, 64);
        if (lane == 0) partial[blockIdx.y * NFEAT + f] = sl1;
    }
}

__global__ __launch_bounds__(256)
void hist_final(const float* __restrict__ partial, const int* __restrict__ ncls,
                float* __restrict__ out) {
    const int tid = threadIdx.x;
    const int lane = tid & 63;
    const int wave = tid >> 6;
    __shared__ double sd[4];

    double s = 0.0;
    for (int i = tid; i < ACTC * NFEAT; i += 256) s += (double)partial[i];
    for (int off = 32; off; off >>= 1) s += __shfl_down(s, off, 64);
    if (lane == 0) sd[wave] = s;
    __syncthreads();
    if (tid == 0) {
        double tot = sd[0] + sd[1] + sd[2] + sd[3];
        int active = 0;
        for (int c = 1; c < NCLS; ++c) active += (ncls[c] > 0) ? 1 : 0;
        double loss = tot / (double)(NFEAT * BINS);
        loss = loss / ((double)active + 1e-12);
        out[0] = (float)loss;
    }
}

extern "C" void kernel_launch(void* const* d_in, const int* in_sizes, int n_in,
                              void* d_out, int out_size, void* d_ws, size_t ws_size,
                              hipStream_t stream) {
    const float* x   = (const float*)d_in[0];
    const int*   lab = (const int*)d_in[1];
    float* out       = (float*)d_out;
    float* partial   = (float*)d_ws;
    int*   ncls      = (int*)((char*)d_ws + (size_t)ACTC * NFEAT * sizeof(float));

    dim3 grid(NFEAT, ACTC);
    hipLaunchKernelGGL(hist_main, grid, dim3(256), 0, stream, x, lab, partial, ncls);
    hipLaunchKernelGGL(hist_final, dim3(1), dim3(256), 0, stream, partial, ncls, out);
}